// Round 1
// baseline (169.430 us; speedup 1.0000x reference)
//
#include <hip/hip_runtime.h>
#include <stdint.h>

typedef float f32x4 __attribute__((ext_vector_type(4)));
typedef unsigned short u16x4 __attribute__((ext_vector_type(4)));
typedef unsigned short u16x8 __attribute__((ext_vector_type(8)));
typedef __bf16 bf16x8 __attribute__((ext_vector_type(8)));

// ---------- helpers ----------
__device__ __forceinline__ unsigned short f2bf(float f) {
  unsigned u = __float_as_uint(f);
  u += 0x7fffu + ((u >> 16) & 1u);   // RNE; inputs are finite (no NaN handling needed)
  return (unsigned short)(u >> 16);
}
__device__ __forceinline__ float bf2f(unsigned short h) {
  return __uint_as_float(((unsigned)h) << 16);
}
__device__ __forceinline__ f32x4 mfma16x16x32(u16x8 a, u16x8 b, f32x4 c) {
  return __builtin_amdgcn_mfma_f32_16x16x32_bf16(
      __builtin_bit_cast(bf16x8, a), __builtin_bit_cast(bf16x8, b), c, 0, 0, 0);
}
__device__ __forceinline__ void gload_lds16(const unsigned short* g, unsigned short* l) {
  __builtin_amdgcn_global_load_lds((__attribute__((address_space(1))) void*)(g),
                                   (__attribute__((address_space(3))) void*)(l), 16, 0, 0);
}

// ---------- weight fp32 -> bf16 cast (all 4 weight matrices packed) ----------
__global__ __launch_bounds__(256)
void cvt_weights(const float* __restrict__ wq, const float* __restrict__ wo,
                 const float* __restrict__ w1, const float* __restrict__ w2,
                 unsigned short* __restrict__ dst) {
  int i4 = blockIdx.x * 256 + threadIdx.x;     // 786432 float4 units total
  int e = i4 << 2;
  const float* src; int off;
  if (e < 786432)       { src = wq; off = 0; }
  else if (e < 1048576) { src = wo; off = 786432; }
  else if (e < 2097152) { src = w1; off = 1048576; }
  else                  { src = w2; off = 2097152; }
  int le = e - off;
  f32x4 v = *(const f32x4*)(src + le);
  u16x4 o;
  #pragma unroll
  for (int i = 0; i < 4; ++i) o[i] = f2bf(v[i]);
  *(u16x4*)(dst + e) = o;
}

// ---------- LayerNorm (fp32 in) -> bf16 out; one wave per 512-dim row ----------
__global__ __launch_bounds__(256)
void ln_bf16(const float* __restrict__ x, const float* __restrict__ w,
             const float* __restrict__ b, unsigned short* __restrict__ out) {
  const int row = (blockIdx.x << 2) + (threadIdx.x >> 6);
  const int lane = threadIdx.x & 63;
  const float* xr = x + (size_t)row * 512 + (lane << 3);
  f32x4 v0 = *(const f32x4*)xr;
  f32x4 v1 = *(const f32x4*)(xr + 4);
  float s = 0.f, s2 = 0.f;
  #pragma unroll
  for (int i = 0; i < 4; ++i) { s += v0[i] + v1[i]; s2 += v0[i]*v0[i] + v1[i]*v1[i]; }
  #pragma unroll
  for (int m = 1; m < 64; m <<= 1) { s += __shfl_xor(s, m); s2 += __shfl_xor(s2, m); }
  float mean = s * (1.0f / 512.0f);
  float var  = s2 * (1.0f / 512.0f) - mean * mean;
  float rs = rsqrtf(var + 1e-5f);
  const int d = lane << 3;
  u16x8 o;
  #pragma unroll
  for (int i = 0; i < 8; ++i) {
    float xv = (i < 4) ? v0[i] : v1[i - 4];
    o[i] = f2bf((xv - mean) * rs * w[d + i] + b[d + i]);
  }
  *(u16x8*)(out + (size_t)row * 512 + d) = o;
}

// ---------- GEMM: C[M,N] = A[M,K](bf16,rm) * B[N,K](bf16,rm)^T + epilogue ----------
// EPI 0: +bias -> bf16 (QKV)   EPI 1: +bias+resid -> fp32   EPI 2: +bias, GELU -> bf16
template<int EPI>
__global__ __launch_bounds__(256)
void gemm_bt(const unsigned short* __restrict__ A, const unsigned short* __restrict__ B,
             const float* __restrict__ bias, const float* __restrict__ resid,
             float* __restrict__ Cf, unsigned short* __restrict__ Cb,
             int M, int N, int K) {
  __shared__ __align__(16) unsigned short lA[128 * 64];
  __shared__ __align__(16) unsigned short lB[128 * 64];
  const int tid = threadIdx.x;
  const int wave = tid >> 6, lane = tid & 63;
  const int gn = N >> 7;
  const int tm = blockIdx.x / gn, tn = blockIdx.x - tm * gn;
  const int m0 = tm << 7, n0 = tn << 7;
  const int wr = wave >> 1, wc = wave & 1;
  const int lr = lane & 15;
  const int lk = (lane >> 4) << 3;
  const int srow = tid >> 3;             // staging row (per 32-row chunk)
  const int scol = (tid & 7) << 3;       // staging k-offset (8 bf16 = 16B)
  f32x4 acc[4][4] = {};
  for (int k0 = 0; k0 < K; k0 += 64) {
    #pragma unroll
    for (int it = 0; it < 4; ++it) {
      int r = (it << 5) + srow;
      // LDS dest is wave-uniform; HW adds lane*16B. chunk c = it*256+tid -> lds elem c*8.
      gload_lds16(A + (size_t)(m0 + r) * K + k0 + scol, &lA[((it << 8) + (wave << 6)) << 3]);
      gload_lds16(B + (size_t)(n0 + r) * K + k0 + scol, &lB[((it << 8) + (wave << 6)) << 3]);
    }
    __syncthreads();
    #pragma unroll
    for (int kk = 0; kk < 64; kk += 32) {
      u16x8 af[4], bfv[4];
      #pragma unroll
      for (int m = 0; m < 4; ++m)
        af[m] = *(const u16x8*)&lA[((wr << 6) + (m << 4) + lr) * 64 + kk + lk];
      #pragma unroll
      for (int n = 0; n < 4; ++n)
        bfv[n] = *(const u16x8*)&lB[((wc << 6) + (n << 4) + lr) * 64 + kk + lk];
      #pragma unroll
      for (int m = 0; m < 4; ++m)
        #pragma unroll
        for (int n = 0; n < 4; ++n)
          acc[m][n] = mfma16x16x32(af[m], bfv[n], acc[m][n]);
    }
    __syncthreads();
  }
  const int rbase = m0 + (wr << 6) + ((lane >> 4) << 2);
  const int cbase = n0 + (wc << 6) + lr;
  #pragma unroll
  for (int m = 0; m < 4; ++m) {
    #pragma unroll
    for (int n = 0; n < 4; ++n) {
      int col = cbase + (n << 4);
      float bcol = bias[col];
      #pragma unroll
      for (int i = 0; i < 4; ++i) {
        int row = rbase + (m << 4) + i;
        float v = acc[m][n][i] + bcol;
        size_t off = (size_t)row * N + col;
        if (EPI == 0) {
          Cb[off] = f2bf(v);
        } else if (EPI == 1) {
          Cf[off] = v + resid[off];
        } else {
          float g = 0.5f * v * (1.0f + erff(v * 0.70710678f));
          Cb[off] = f2bf(g);
        }
      }
    }
  }
}

// ---------- dilated windowed causal attention ----------
// DIL=2 => two independent causal sliding-window (129-key) attentions over the
// even/odd subsequences (length 1024). Block = (b, h, parity, 64 q' tile).
__global__ __launch_bounds__(256)
void attn_win(const unsigned short* __restrict__ qkv, unsigned short* __restrict__ out) {
  __shared__ __align__(16) unsigned short Kl[192 * 80];
  __shared__ __align__(16) unsigned short Vl[192 * 80];
  __shared__ float pbuf[4][132];
  const int bid = blockIdx.x;
  const int qt  = bid & 15;
  const int par = (bid >> 4) & 1;
  const int h   = (bid >> 5) & 7;
  const int b   = bid >> 8;
  const int q0  = qt << 6;
  const int tid = threadIdx.x, wave = tid >> 6, lane = tid & 63;
  // stage K,V rows k' = q0-128 .. q0+63 (zero rows with k' < 0: avoids NaN garbage)
  for (int c = tid; c < 192 * 16; c += 256) {
    int r = c >> 4, cc = (c & 15) << 2;
    int kp = q0 - 128 + r;
    u16x4 kb = {0, 0, 0, 0}, vb = {0, 0, 0, 0};
    if (kp >= 0) {
      size_t base = ((size_t)((b << 11) + (kp << 1) + par)) * 1536 + (h << 6) + cc;
      kb = *(const u16x4*)(qkv + base + 512);
      vb = *(const u16x4*)(qkv + base + 1024);
    }
    *(u16x4*)&Kl[r * 80 + cc] = kb;
    *(u16x4*)&Vl[r * 80 + cc] = vb;
  }
  __syncthreads();
  const int grp = lane >> 4, dg = lane & 15;
  for (int qq = 0; qq < 16; ++qq) {
    const int ql = (wave << 4) + qq;     // local query in [0,64)
    const int qp = q0 + ql;              // q' in [0,1024)
    const size_t qbase = ((size_t)((b << 11) + (qp << 1) + par)) * 1536 + (h << 6);
    float qf[64];
    #pragma unroll
    for (int c8 = 0; c8 < 8; ++c8) {
      u16x8 qv = *(const u16x8*)(qkv + qbase + (c8 << 3));   // broadcast load
      #pragma unroll
      for (int e = 0; e < 8; ++e) qf[(c8 << 3) + e] = bf2f(qv[e]);
    }
    // scores: lane holds key offsets j = lane, j = 64+lane, (lane 0: j = 128)
    float sd0 = 0.f, sd1 = 0.f, sd2 = 0.f;
    const int r0 = ql + 128 - lane, r1 = ql + 64 - lane;
    #pragma unroll
    for (int c8 = 0; c8 < 8; ++c8) {
      u16x8 k0v = *(const u16x8*)&Kl[r0 * 80 + (c8 << 3)];
      u16x8 k1v = *(const u16x8*)&Kl[r1 * 80 + (c8 << 3)];
      #pragma unroll
      for (int e = 0; e < 8; ++e) {
        sd0 += qf[(c8 << 3) + e] * bf2f(k0v[e]);
        sd1 += qf[(c8 << 3) + e] * bf2f(k1v[e]);
      }
    }
    if (qp >= 128) {
      #pragma unroll
      for (int c8 = 0; c8 < 8; ++c8) {
        u16x8 k2v = *(const u16x8*)&Kl[ql * 80 + (c8 << 3)];
        #pragma unroll
        for (int e = 0; e < 8; ++e) sd2 += qf[(c8 << 3) + e] * bf2f(k2v[e]);
      }
    }
    sd0 *= 0.125f; sd1 *= 0.125f; sd2 *= 0.125f;
    const bool v0 = (lane <= qp), v1 = (lane + 64 <= qp), v2 = (lane == 0) && (qp >= 128);
    float s0 = v0 ? sd0 : -1e30f, s1 = v1 ? sd1 : -1e30f, s2 = v2 ? sd2 : -1e30f;
    float mm = fmaxf(s0, fmaxf(s1, s2));
    #pragma unroll
    for (int m = 1; m < 64; m <<= 1) mm = fmaxf(mm, __shfl_xor(mm, m));
    float p0 = v0 ? __expf(s0 - mm) : 0.0f;
    float p1 = v1 ? __expf(s1 - mm) : 0.0f;
    float p2 = v2 ? __expf(s2 - mm) : 0.0f;
    float ls = p0 + p1 + p2;
    #pragma unroll
    for (int m = 1; m < 64; m <<= 1) ls += __shfl_xor(ls, m);
    pbuf[wave][lane] = p0;
    pbuf[wave][64 + lane] = p1;
    if (lane < 4) pbuf[wave][128 + lane] = (lane == 0) ? p2 : 0.0f;
    // PV: lanes = (key-group, 4 dims); 33 iterations of 4 keys
    f32x4 o = {0.f, 0.f, 0.f, 0.f};
    for (int jb = 0; jb < 132; jb += 4) {
      int j = jb + grp;
      float p = pbuf[wave][j];
      int r = ql + 128 - j; if (r < 0) r = 0;
      u16x4 vv = *(const u16x4*)&Vl[r * 80 + (dg << 2)];
      #pragma unroll
      for (int e = 0; e < 4; ++e) o[e] += p * bf2f(vv[e]);
    }
    #pragma unroll
    for (int e = 0; e < 4; ++e) {
      o[e] += __shfl_xor(o[e], 16);
      o[e] += __shfl_xor(o[e], 32);
    }
    float inv = 1.0f / ls;
    if (grp == 0) {
      u16x4 ob;
      #pragma unroll
      for (int e = 0; e < 4; ++e) ob[e] = f2bf(o[e] * inv);
      size_t obase = ((size_t)((b << 11) + (qp << 1) + par)) * 512 + (h << 6) + (dg << 2);
      *(u16x4*)(out + obase) = ob;
    }
  }
}

// ---------- launch ----------
extern "C" void kernel_launch(void* const* d_in, const int* in_sizes, int n_in,
                              void* d_out, int out_size, void* d_ws, size_t ws_size,
                              hipStream_t stream) {
  const float* x     = (const float*)d_in[0];
  const float* n1w   = (const float*)d_in[1];
  const float* n1b   = (const float*)d_in[2];
  const float* qkv_w = (const float*)d_in[3];
  const float* qkv_b = (const float*)d_in[4];
  const float* out_w = (const float*)d_in[5];
  const float* out_b = (const float*)d_in[6];
  const float* n2w   = (const float*)d_in[7];
  const float* n2b   = (const float*)d_in[8];
  const float* w1    = (const float*)d_in[9];
  const float* b1    = (const float*)d_in[10];
  const float* w2    = (const float*)d_in[11];
  const float* b2    = (const float*)d_in[12];

  char* ws = (char*)d_ws;
  unsigned short* wbf   = (unsigned short*)(ws);            // packed bf16 weights, 6.25 MB
  unsigned short* wq_bf = wbf;                              // [1536,512]
  unsigned short* wo_bf = (unsigned short*)(ws + 1572864);  // [512,512]
  unsigned short* w1_bf = (unsigned short*)(ws + 2097152);  // [2048,512]
  unsigned short* w2_bf = (unsigned short*)(ws + 4194304);  // [512,2048]
  unsigned short* h_bf  = (unsigned short*)(ws + 6291456);  // [4096,512] (reused for LN2)
  unsigned short* qkvb  = (unsigned short*)(ws + 10485760); // [4096,1536] bf16
  unsigned short* ao_bf = (unsigned short*)(ws + 23068672); // [4096,512] bf16
  float*          x1    = (float*)(ws + 27262976);          // [4096,512] fp32
  unsigned short* f1_bf = (unsigned short*)(ws + 10485760); // [4096,2048] aliases dead qkv+ao
  float* outp = (float*)d_out;

  cvt_weights<<<3072, 256, 0, stream>>>(qkv_w, out_w, w1, w2, wbf);
  ln_bf16<<<1024, 256, 0, stream>>>(x, n1w, n1b, h_bf);
  gemm_bt<0><<<32 * 12, 256, 0, stream>>>(h_bf, wq_bf, qkv_b, nullptr, nullptr, qkvb,
                                          4096, 1536, 512);
  attn_win<<<512, 256, 0, stream>>>(qkvb, ao_bf);
  gemm_bt<1><<<32 * 4, 256, 0, stream>>>(ao_bf, wo_bf, out_b, x, x1, nullptr,
                                         4096, 512, 512);
  ln_bf16<<<1024, 256, 0, stream>>>(x1, n2w, n2b, h_bf);
  gemm_bt<2><<<32 * 16, 256, 0, stream>>>(h_bf, w1_bf, b1, nullptr, nullptr, f1_bf,
                                          4096, 2048, 512);
  gemm_bt<1><<<32 * 4, 256, 0, stream>>>(f1_bf, w2_bf, b2, x1, outp, nullptr,
                                         4096, 512, 2048);
}

// Round 2
// 127.456 us; speedup vs baseline: 1.3293x; 1.3293x over previous
//
#include <hip/hip_runtime.h>
#include <stdint.h>

typedef float f32x4 __attribute__((ext_vector_type(4)));
typedef unsigned short u16x4 __attribute__((ext_vector_type(4)));
typedef unsigned short u16x8 __attribute__((ext_vector_type(8)));
typedef __bf16 bf16x8 __attribute__((ext_vector_type(8)));

// ---------- helpers ----------
__device__ __forceinline__ unsigned short f2bf(float f) {
  unsigned u = __float_as_uint(f);
  u += 0x7fffu + ((u >> 16) & 1u);   // RNE; inputs finite
  return (unsigned short)(u >> 16);
}
__device__ __forceinline__ float bf2f(unsigned short h) {
  return __uint_as_float(((unsigned)h) << 16);
}
__device__ __forceinline__ f32x4 mfma16x16x32(u16x8 a, u16x8 b, f32x4 c) {
  return __builtin_amdgcn_mfma_f32_16x16x32_bf16(
      __builtin_bit_cast(bf16x8, a), __builtin_bit_cast(bf16x8, b), c, 0, 0, 0);
}
__device__ __forceinline__ void gload_lds16(const unsigned short* g, unsigned short* l) {
  __builtin_amdgcn_global_load_lds((__attribute__((address_space(1))) void*)(g),
                                   (__attribute__((address_space(3))) void*)(l), 16, 0, 0);
}

// ---------- weight fp32 -> bf16 cast ----------
__global__ __launch_bounds__(256)
void cvt_weights(const float* __restrict__ wq, const float* __restrict__ wo,
                 const float* __restrict__ w1, const float* __restrict__ w2,
                 unsigned short* __restrict__ dst) {
  int i4 = blockIdx.x * 256 + threadIdx.x;
  int e = i4 << 2;
  const float* src; int off;
  if (e < 786432)       { src = wq; off = 0; }
  else if (e < 1048576) { src = wo; off = 786432; }
  else if (e < 2097152) { src = w1; off = 1048576; }
  else                  { src = w2; off = 2097152; }
  int le = e - off;
  f32x4 v = *(const f32x4*)(src + le);
  u16x4 o;
  #pragma unroll
  for (int i = 0; i < 4; ++i) o[i] = f2bf(v[i]);
  *(u16x4*)(dst + e) = o;
}

// ---------- LayerNorm (fp32 in) -> bf16 out ----------
__global__ __launch_bounds__(256)
void ln_bf16(const float* __restrict__ x, const float* __restrict__ w,
             const float* __restrict__ b, unsigned short* __restrict__ out) {
  const int row = (blockIdx.x << 2) + (threadIdx.x >> 6);
  const int lane = threadIdx.x & 63;
  const float* xr = x + (size_t)row * 512 + (lane << 3);
  f32x4 v0 = *(const f32x4*)xr;
  f32x4 v1 = *(const f32x4*)(xr + 4);
  float s = 0.f, s2 = 0.f;
  #pragma unroll
  for (int i = 0; i < 4; ++i) { s += v0[i] + v1[i]; s2 += v0[i]*v0[i] + v1[i]*v1[i]; }
  #pragma unroll
  for (int m = 1; m < 64; m <<= 1) { s += __shfl_xor(s, m); s2 += __shfl_xor(s2, m); }
  float mean = s * (1.0f / 512.0f);
  float var  = s2 * (1.0f / 512.0f) - mean * mean;
  float rs = rsqrtf(var + 1e-5f);
  const int d = lane << 3;
  u16x8 o;
  #pragma unroll
  for (int i = 0; i < 8; ++i) {
    float xv = (i < 4) ? v0[i] : v1[i - 4];
    o[i] = f2bf((xv - mean) * rs * w[d + i] + b[d + i]);
  }
  *(u16x8*)(out + (size_t)row * 512 + d) = o;
}

// ---------- GEMM: C[M,N] = A[M,K](bf16,rm) * B[N,K](bf16,rm)^T + epilogue ----------
template<int EPI>
__global__ __launch_bounds__(256)
void gemm_bt(const unsigned short* __restrict__ A, const unsigned short* __restrict__ B,
             const float* __restrict__ bias, const float* __restrict__ resid,
             float* __restrict__ Cf, unsigned short* __restrict__ Cb,
             int M, int N, int K) {
  __shared__ __align__(16) unsigned short lA[128 * 64];
  __shared__ __align__(16) unsigned short lB[128 * 64];
  const int tid = threadIdx.x;
  const int wave = tid >> 6, lane = tid & 63;
  const int gn = N >> 7;
  const int tm = blockIdx.x / gn, tn = blockIdx.x - tm * gn;
  const int m0 = tm << 7, n0 = tn << 7;
  const int wr = wave >> 1, wc = wave & 1;
  const int lr = lane & 15;
  const int lk = (lane >> 4) << 3;
  const int srow = tid >> 3;
  const int scol = (tid & 7) << 3;
  f32x4 acc[4][4] = {};
  for (int k0 = 0; k0 < K; k0 += 64) {
    #pragma unroll
    for (int it = 0; it < 4; ++it) {
      int r = (it << 5) + srow;
      gload_lds16(A + (size_t)(m0 + r) * K + k0 + scol, &lA[((it << 8) + (wave << 6)) << 3]);
      gload_lds16(B + (size_t)(n0 + r) * K + k0 + scol, &lB[((it << 8) + (wave << 6)) << 3]);
    }
    __syncthreads();
    #pragma unroll
    for (int kk = 0; kk < 64; kk += 32) {
      u16x8 af[4], bfv[4];
      #pragma unroll
      for (int m = 0; m < 4; ++m)
        af[m] = *(const u16x8*)&lA[((wr << 6) + (m << 4) + lr) * 64 + kk + lk];
      #pragma unroll
      for (int n = 0; n < 4; ++n)
        bfv[n] = *(const u16x8*)&lB[((wc << 6) + (n << 4) + lr) * 64 + kk + lk];
      #pragma unroll
      for (int m = 0; m < 4; ++m)
        #pragma unroll
        for (int n = 0; n < 4; ++n)
          acc[m][n] = mfma16x16x32(af[m], bfv[n], acc[m][n]);
    }
    __syncthreads();
  }
  const int rbase = m0 + (wr << 6) + ((lane >> 4) << 2);
  const int cbase = n0 + (wc << 6) + lr;
  #pragma unroll
  for (int m = 0; m < 4; ++m) {
    #pragma unroll
    for (int n = 0; n < 4; ++n) {
      int col = cbase + (n << 4);
      float bcol = bias[col];
      #pragma unroll
      for (int i = 0; i < 4; ++i) {
        int row = rbase + (m << 4) + i;
        float v = acc[m][n][i] + bcol;
        size_t off = (size_t)row * N + col;
        if (EPI == 0) {
          Cb[off] = f2bf(v);
        } else if (EPI == 1) {
          Cf[off] = v + resid[off];
        } else {
          float g = 0.5f * v * (1.0f + erff(v * 0.70710678f));
          Cb[off] = f2bf(g);
        }
      }
    }
  }
}

// ---------- MFMA dilated windowed causal attention ----------
// DIL=2: two independent causal 129-key sliding-window attentions over the
// even/odd subsequences (len 1024). Block = (b,h,par, 64-query span); 4 waves,
// each wave owns a 16-query tile attending to 144 keys (9 QK tiles, 5 PV
// k-steps with K-dim padded to 160; P pad cols and Vt pad rows are zeroed).
__global__ __launch_bounds__(256)
void attn_mfma(const unsigned short* __restrict__ qkv, unsigned short* __restrict__ out) {
  __shared__ __align__(16) unsigned short Vt[64 * 216];      // V^T: [d][k], ld=216
  __shared__ __align__(16) unsigned short Pl[4][16 * 168];   // per-wave P: [q][k], ld=168
  const int bid = blockIdx.x;
  const int qt  = bid & 15;
  const int par = (bid >> 4) & 1;
  const int h   = (bid >> 5) & 7;
  const int b   = bid >> 8;
  const int q0  = qt << 6;
  const int tid = threadIdx.x, wave = tid >> 6, lane = tid & 63;

  // stage V transposed: rows r=0..191 are keys q0-128..q0+63; r=192..207 zero pad
  for (int c = tid; c < 208 * 16; c += 256) {
    int r = c >> 4, dc = (c & 15) << 2;
    int kp = q0 - 128 + r;
    u16x4 vb = {0, 0, 0, 0};
    if (r < 192 && kp >= 0) {
      size_t base = ((size_t)((b << 11) + (kp << 1) + par)) * 1536 + 1024 + (h << 6) + dc;
      vb = *(const u16x4*)(qkv + base);
    }
    #pragma unroll
    for (int e = 0; e < 4; ++e) Vt[(dc + e) * 216 + r] = vb[e];
  }
  __syncthreads();

  const int col = lane & 15;         // frag row/col index
  const int rg  = lane >> 4;         // frag k-group / row-group
  const int qt0 = q0 + (wave << 4);  // this wave's first query (subseq coords)
  unsigned short* Pw = Pl[wave];

  // Q a-fragments direct from global
  const long long qrow = (long long)((b << 11) + ((qt0 + col) << 1) + par);
  const unsigned short* qp = qkv + qrow * 1536 + (h << 6) + (rg << 3);
  u16x8 qa0 = *(const u16x8*)(qp);
  u16x8 qa1 = *(const u16x8*)(qp + 32);

  // QK^T: 9 key sub-tiles, K b-frags direct from global (signed offset; kp<0
  // lands in earlier ws regions -> garbage, masked below)
  f32x4 sc[9];
  #pragma unroll
  for (int j = 0; j < 9; ++j) sc[j] = (f32x4){0.f, 0.f, 0.f, 0.f};
  #pragma unroll
  for (int j = 0; j < 9; ++j) {
    int kpj = qt0 - 128 + (j << 4) + col;
    long long krow = (long long)((b << 11) + (kpj << 1) + par);
    const unsigned short* kp = qkv + krow * 1536 + 512 + (h << 6) + (rg << 3);
    u16x8 k0 = *(const u16x8*)(kp);
    u16x8 k1 = *(const u16x8*)(kp + 32);
    sc[j] = mfma16x16x32(qa0, k0, sc[j]);
    sc[j] = mfma16x16x32(qa1, k1, sc[j]);
  }

  // mask + scale + row max (rows live in (rg,i); cols in lane bits 0-3)
  float mrow[4] = {-3e38f, -3e38f, -3e38f, -3e38f};
  #pragma unroll
  for (int j = 0; j < 9; ++j) {
    #pragma unroll
    for (int i = 0; i < 4; ++i) {
      int qr = (rg << 2) + i;
      int jk = (j << 4) + col;
      bool ok = (jk >= qr) && (jk <= qr + 128) && (qt0 + jk >= 128);
      float s = ok ? sc[j][i] * 0.125f : -1e30f;
      sc[j][i] = s;
      mrow[i] = fmaxf(mrow[i], s);
    }
  }
  #pragma unroll
  for (int i = 0; i < 4; ++i)
    #pragma unroll
    for (int m = 1; m < 16; m <<= 1) mrow[i] = fmaxf(mrow[i], __shfl_xor(mrow[i], m));

  // exp, row sum, write P (bf16) to wave-local LDS
  float lrow[4] = {0.f, 0.f, 0.f, 0.f};
  #pragma unroll
  for (int j = 0; j < 9; ++j) {
    #pragma unroll
    for (int i = 0; i < 4; ++i) {
      float p = __expf(sc[j][i] - mrow[i]);   // masked -> exp(-huge) = 0
      lrow[i] += p;
      Pw[((rg << 2) + i) * 168 + (j << 4) + col] = f2bf(p);
    }
  }
  #pragma unroll
  for (int i = 0; i < 4; ++i)
    Pw[((rg << 2) + i) * 168 + 144 + col] = 0;   // zero pad cols 144..159
  #pragma unroll
  for (int i = 0; i < 4; ++i)
    #pragma unroll
    for (int m = 1; m < 16; m <<= 1) lrow[i] += __shfl_xor(lrow[i], m);
  float inv[4];
  #pragma unroll
  for (int i = 0; i < 4; ++i) inv[i] = 1.0f / lrow[i];

  // PV: O[16x64] = P[16x160] * Vt^T
  f32x4 oacc[4] = {};
  #pragma unroll
  for (int ks = 0; ks < 5; ++ks) {
    int kk = ks << 5;
    u16x8 pa = *(const u16x8*)&Pw[col * 168 + kk + (rg << 3)];
    #pragma unroll
    for (int n = 0; n < 4; ++n) {
      u16x8 vb = *(const u16x8*)&Vt[((n << 4) + col) * 216 + (wave << 4) + kk + (rg << 3)];
      oacc[n] = mfma16x16x32(pa, vb, oacc[n]);
    }
  }

  // epilogue: normalize, store bf16
  #pragma unroll
  for (int n = 0; n < 4; ++n) {
    #pragma unroll
    for (int i = 0; i < 4; ++i) {
      int q = qt0 + (rg << 2) + i;
      size_t off = ((size_t)((b << 11) + (q << 1) + par)) * 512 + (h << 6) + (n << 4) + col;
      out[off] = f2bf(oacc[n][i] * inv[i]);
    }
  }
}

// ---------- launch ----------
extern "C" void kernel_launch(void* const* d_in, const int* in_sizes, int n_in,
                              void* d_out, int out_size, void* d_ws, size_t ws_size,
                              hipStream_t stream) {
  const float* x     = (const float*)d_in[0];
  const float* n1w   = (const float*)d_in[1];
  const float* n1b   = (const float*)d_in[2];
  const float* qkv_w = (const float*)d_in[3];
  const float* qkv_b = (const float*)d_in[4];
  const float* out_w = (const float*)d_in[5];
  const float* out_b = (const float*)d_in[6];
  const float* n2w   = (const float*)d_in[7];
  const float* n2b   = (const float*)d_in[8];
  const float* w1    = (const float*)d_in[9];
  const float* b1    = (const float*)d_in[10];
  const float* w2    = (const float*)d_in[11];
  const float* b2    = (const float*)d_in[12];

  char* ws = (char*)d_ws;
  unsigned short* wbf   = (unsigned short*)(ws);
  unsigned short* wq_bf = wbf;                              // [1536,512]
  unsigned short* wo_bf = (unsigned short*)(ws + 1572864);  // [512,512]
  unsigned short* w1_bf = (unsigned short*)(ws + 2097152);  // [2048,512]
  unsigned short* w2_bf = (unsigned short*)(ws + 4194304);  // [512,2048]
  unsigned short* h_bf  = (unsigned short*)(ws + 6291456);  // [4096,512]
  unsigned short* qkvb  = (unsigned short*)(ws + 10485760); // [4096,1536] bf16
  unsigned short* ao_bf = (unsigned short*)(ws + 23068672); // [4096,512] bf16
  float*          x1    = (float*)(ws + 27262976);          // [4096,512] fp32
  unsigned short* f1_bf = (unsigned short*)(ws + 10485760); // [4096,2048] aliases dead qkv+ao
  float* outp = (float*)d_out;

  cvt_weights<<<3072, 256, 0, stream>>>(qkv_w, out_w, w1, w2, wbf);
  ln_bf16<<<1024, 256, 0, stream>>>(x, n1w, n1b, h_bf);
  gemm_bt<0><<<32 * 12, 256, 0, stream>>>(h_bf, wq_bf, qkv_b, nullptr, nullptr, qkvb,
                                          4096, 1536, 512);
  attn_mfma<<<512, 256, 0, stream>>>(qkvb, ao_bf);
  gemm_bt<1><<<32 * 4, 256, 0, stream>>>(ao_bf, wo_bf, out_b, x, x1, nullptr,
                                         4096, 512, 512);
  ln_bf16<<<1024, 256, 0, stream>>>(x1, n2w, n2b, h_bf);
  gemm_bt<2><<<32 * 16, 256, 0, stream>>>(h_bf, w1_bf, b1, nullptr, nullptr, f1_bf,
                                          4096, 2048, 512);
  gemm_bt<1><<<32 * 4, 256, 0, stream>>>(f1_bf, w2_bf, b2, x1, outp, nullptr,
                                         4096, 512, 2048);
}

// Round 3
// 104.720 us; speedup vs baseline: 1.6179x; 1.2171x over previous
//
#include <hip/hip_runtime.h>
#include <stdint.h>

typedef float f32x4 __attribute__((ext_vector_type(4)));
typedef unsigned short u16x4 __attribute__((ext_vector_type(4)));
typedef unsigned short u16x8 __attribute__((ext_vector_type(8)));
typedef __bf16 bf16x8 __attribute__((ext_vector_type(8)));

// ---------- helpers ----------
__device__ __forceinline__ unsigned short f2bf(float f) {
  unsigned u = __float_as_uint(f);
  u += 0x7fffu + ((u >> 16) & 1u);   // RNE; inputs finite
  return (unsigned short)(u >> 16);
}
__device__ __forceinline__ float bf2f(unsigned short h) {
  return __uint_as_float(((unsigned)h) << 16);
}
__device__ __forceinline__ f32x4 mfma16x16x32(u16x8 a, u16x8 b, f32x4 c) {
  return __builtin_amdgcn_mfma_f32_16x16x32_bf16(
      __builtin_bit_cast(bf16x8, a), __builtin_bit_cast(bf16x8, b), c, 0, 0, 0);
}
__device__ __forceinline__ void gload_lds16(const unsigned short* g, unsigned short* l) {
  __builtin_amdgcn_global_load_lds((__attribute__((address_space(1))) void*)(g),
                                   (__attribute__((address_space(3))) void*)(l), 16, 0, 0);
}

// ---------- weight fp32 -> bf16 cast ----------
__global__ __launch_bounds__(256)
void cvt_weights(const float* __restrict__ wq, const float* __restrict__ wo,
                 const float* __restrict__ w1, const float* __restrict__ w2,
                 unsigned short* __restrict__ dst) {
  int i4 = blockIdx.x * 256 + threadIdx.x;
  int e = i4 << 2;
  const float* src; int off;
  if (e < 786432)       { src = wq; off = 0; }
  else if (e < 1048576) { src = wo; off = 786432; }
  else if (e < 2097152) { src = w1; off = 1048576; }
  else                  { src = w2; off = 2097152; }
  int le = e - off;
  f32x4 v = *(const f32x4*)(src + le);
  u16x4 o;
  #pragma unroll
  for (int i = 0; i < 4; ++i) o[i] = f2bf(v[i]);
  *(u16x4*)(dst + e) = o;
}

// ---------- LayerNorm (fp32 in) -> bf16 out ----------
__global__ __launch_bounds__(256)
void ln_bf16(const float* __restrict__ x, const float* __restrict__ w,
             const float* __restrict__ b, unsigned short* __restrict__ out) {
  const int row = (blockIdx.x << 2) + (threadIdx.x >> 6);
  const int lane = threadIdx.x & 63;
  const float* xr = x + (size_t)row * 512 + (lane << 3);
  f32x4 v0 = *(const f32x4*)xr;
  f32x4 v1 = *(const f32x4*)(xr + 4);
  float s = 0.f, s2 = 0.f;
  #pragma unroll
  for (int i = 0; i < 4; ++i) { s += v0[i] + v1[i]; s2 += v0[i]*v0[i] + v1[i]*v1[i]; }
  #pragma unroll
  for (int m = 1; m < 64; m <<= 1) { s += __shfl_xor(s, m); s2 += __shfl_xor(s2, m); }
  float mean = s * (1.0f / 512.0f);
  float var  = s2 * (1.0f / 512.0f) - mean * mean;
  float rs = rsqrtf(var + 1e-5f);
  const int d = lane << 3;
  u16x8 o;
  #pragma unroll
  for (int i = 0; i < 8; ++i) {
    float xv = (i < 4) ? v0[i] : v1[i - 4];
    o[i] = f2bf((xv - mean) * rs * w[d + i] + b[d + i]);
  }
  *(u16x8*)(out + (size_t)row * 512 + d) = o;
}

// ---------- GEMM: C[M,N] = A[M,K](bf16,rm) * B[N,K](bf16,rm)^T + epilogue ----------
// Tiled BMxBN, 4 waves in 2x2, per-wave (BM/2)x(BN/2), BK=64.
// EPI 0: +bias -> bf16   EPI 1: +bias+resid -> fp32   EPI 2: +bias, GELU -> bf16
template<int BM, int BN, int EPI>
__global__ __launch_bounds__(256)
void gemm_bt(const unsigned short* __restrict__ A, const unsigned short* __restrict__ B,
             const float* __restrict__ bias, const float* __restrict__ resid,
             float* __restrict__ Cf, unsigned short* __restrict__ Cb,
             int M, int N, int K) {
  constexpr int AM = BM / 32, AN = BN / 32;     // per-wave 16x16 frags
  __shared__ __align__(16) unsigned short lA[BM * 64];
  __shared__ __align__(16) unsigned short lB[BN * 64];
  const int tid = threadIdx.x;
  const int wave = tid >> 6, lane = tid & 63;
  const int gn = N / BN;
  const int tm = blockIdx.x / gn, tn = blockIdx.x - tm * gn;
  const int m0 = tm * BM, n0 = tn * BN;
  const int wr = wave >> 1, wc = wave & 1;
  const int lr = lane & 15;
  const int lk = (lane >> 4) << 3;
  const int srow = tid >> 3;             // 0..31 staging row within 32-row chunk
  const int scol = (tid & 7) << 3;       // k-offset (8 bf16 = 16B)
  f32x4 acc[AM][AN] = {};
  for (int k0 = 0; k0 < K; k0 += 64) {
    #pragma unroll
    for (int it = 0; it < BM / 32; ++it)
      gload_lds16(A + (size_t)(m0 + (it << 5) + srow) * K + k0 + scol,
                  &lA[((it << 8) + (wave << 6)) << 3]);
    #pragma unroll
    for (int it = 0; it < BN / 32; ++it)
      gload_lds16(B + (size_t)(n0 + (it << 5) + srow) * K + k0 + scol,
                  &lB[((it << 8) + (wave << 6)) << 3]);
    __syncthreads();
    #pragma unroll
    for (int kk = 0; kk < 64; kk += 32) {
      u16x8 af[AM], bfv[AN];
      #pragma unroll
      for (int m = 0; m < AM; ++m)
        af[m] = *(const u16x8*)&lA[(wr * (BM / 2) + (m << 4) + lr) * 64 + kk + lk];
      #pragma unroll
      for (int n = 0; n < AN; ++n)
        bfv[n] = *(const u16x8*)&lB[(wc * (BN / 2) + (n << 4) + lr) * 64 + kk + lk];
      #pragma unroll
      for (int m = 0; m < AM; ++m)
        #pragma unroll
        for (int n = 0; n < AN; ++n)
          acc[m][n] = mfma16x16x32(af[m], bfv[n], acc[m][n]);
    }
    __syncthreads();
  }
  const int rbase = m0 + wr * (BM / 2) + ((lane >> 4) << 2);
  const int cbase = n0 + wc * (BN / 2) + lr;
  #pragma unroll
  for (int m = 0; m < AM; ++m) {
    #pragma unroll
    for (int n = 0; n < AN; ++n) {
      int col = cbase + (n << 4);
      float bcol = bias[col];
      #pragma unroll
      for (int i = 0; i < 4; ++i) {
        int row = rbase + (m << 4) + i;
        float v = acc[m][n][i] + bcol;
        size_t off = (size_t)row * N + col;
        if (EPI == 0) {
          Cb[off] = f2bf(v);
        } else if (EPI == 1) {
          Cf[off] = v + resid[off];
        } else {
          float g = 0.5f * v * (1.0f + erff(v * 0.70710678f));
          Cb[off] = f2bf(g);
        }
      }
    }
  }
}

// ---------- MFMA dilated windowed causal attention ----------
// DIL=2: two independent causal 129-key sliding-window attentions over the
// even/odd subsequences (len 1024). Block = (b,h,par, 64-query span); 4 waves,
// each wave owns a 16-query tile attending to 144 keys (9 QK tiles, 5 PV
// k-steps with K-dim padded to 160; P pad cols and Vt pad rows are zeroed).
__global__ __launch_bounds__(256)
void attn_mfma(const unsigned short* __restrict__ qkv, unsigned short* __restrict__ out) {
  __shared__ __align__(16) unsigned short Vt[64 * 216];      // V^T: [d][k], ld=216
  __shared__ __align__(16) unsigned short Pl[4][16 * 168];   // per-wave P: [q][k], ld=168
  const int bid = blockIdx.x;
  const int qt  = bid & 15;
  const int par = (bid >> 4) & 1;
  const int h   = (bid >> 5) & 7;
  const int b   = bid >> 8;
  const int q0  = qt << 6;
  const int tid = threadIdx.x, wave = tid >> 6, lane = tid & 63;

  for (int c = tid; c < 208 * 16; c += 256) {
    int r = c >> 4, dc = (c & 15) << 2;
    int kp = q0 - 128 + r;
    u16x4 vb = {0, 0, 0, 0};
    if (r < 192 && kp >= 0) {
      size_t base = ((size_t)((b << 11) + (kp << 1) + par)) * 1536 + 1024 + (h << 6) + dc;
      vb = *(const u16x4*)(qkv + base);
    }
    #pragma unroll
    for (int e = 0; e < 4; ++e) Vt[(dc + e) * 216 + r] = vb[e];
  }
  __syncthreads();

  const int col = lane & 15;
  const int rg  = lane >> 4;
  const int qt0 = q0 + (wave << 4);
  unsigned short* Pw = Pl[wave];

  const long long qrow = (long long)((b << 11) + ((qt0 + col) << 1) + par);
  const unsigned short* qp = qkv + qrow * 1536 + (h << 6) + (rg << 3);
  u16x8 qa0 = *(const u16x8*)(qp);
  u16x8 qa1 = *(const u16x8*)(qp + 32);

  f32x4 sc[9];
  #pragma unroll
  for (int j = 0; j < 9; ++j) sc[j] = (f32x4){0.f, 0.f, 0.f, 0.f};
  #pragma unroll
  for (int j = 0; j < 9; ++j) {
    int kpj = qt0 - 128 + (j << 4) + col;
    long long krow = (long long)((b << 11) + (kpj << 1) + par);
    const unsigned short* kp = qkv + krow * 1536 + 512 + (h << 6) + (rg << 3);
    u16x8 k0 = *(const u16x8*)(kp);
    u16x8 k1 = *(const u16x8*)(kp + 32);
    sc[j] = mfma16x16x32(qa0, k0, sc[j]);
    sc[j] = mfma16x16x32(qa1, k1, sc[j]);
  }

  float mrow[4] = {-3e38f, -3e38f, -3e38f, -3e38f};
  #pragma unroll
  for (int j = 0; j < 9; ++j) {
    #pragma unroll
    for (int i = 0; i < 4; ++i) {
      int qr = (rg << 2) + i;
      int jk = (j << 4) + col;
      bool ok = (jk >= qr) && (jk <= qr + 128) && (qt0 + jk >= 128);
      float s = ok ? sc[j][i] * 0.125f : -1e30f;
      sc[j][i] = s;
      mrow[i] = fmaxf(mrow[i], s);
    }
  }
  #pragma unroll
  for (int i = 0; i < 4; ++i)
    #pragma unroll
    for (int m = 1; m < 16; m <<= 1) mrow[i] = fmaxf(mrow[i], __shfl_xor(mrow[i], m));

  float lrow[4] = {0.f, 0.f, 0.f, 0.f};
  #pragma unroll
  for (int j = 0; j < 9; ++j) {
    #pragma unroll
    for (int i = 0; i < 4; ++i) {
      float p = __expf(sc[j][i] - mrow[i]);
      lrow[i] += p;
      Pw[((rg << 2) + i) * 168 + (j << 4) + col] = f2bf(p);
    }
  }
  #pragma unroll
  for (int i = 0; i < 4; ++i)
    Pw[((rg << 2) + i) * 168 + 144 + col] = 0;
  #pragma unroll
  for (int i = 0; i < 4; ++i)
    #pragma unroll
    for (int m = 1; m < 16; m <<= 1) lrow[i] += __shfl_xor(lrow[i], m);
  float inv[4];
  #pragma unroll
  for (int i = 0; i < 4; ++i) inv[i] = 1.0f / lrow[i];

  f32x4 oacc[4] = {};
  #pragma unroll
  for (int ks = 0; ks < 5; ++ks) {
    int kk = ks << 5;
    u16x8 pa = *(const u16x8*)&Pw[col * 168 + kk + (rg << 3)];
    #pragma unroll
    for (int n = 0; n < 4; ++n) {
      u16x8 vb = *(const u16x8*)&Vt[((n << 4) + col) * 216 + (wave << 4) + kk + (rg << 3)];
      oacc[n] = mfma16x16x32(pa, vb, oacc[n]);
    }
  }

  #pragma unroll
  for (int n = 0; n < 4; ++n) {
    #pragma unroll
    for (int i = 0; i < 4; ++i) {
      int q = qt0 + (rg << 2) + i;
      size_t off = ((size_t)((b << 11) + (q << 1) + par)) * 512 + (h << 6) + (n << 4) + col;
      out[off] = f2bf(oacc[n][i] * inv[i]);
    }
  }
}

// ---------- launch ----------
extern "C" void kernel_launch(void* const* d_in, const int* in_sizes, int n_in,
                              void* d_out, int out_size, void* d_ws, size_t ws_size,
                              hipStream_t stream) {
  const float* x     = (const float*)d_in[0];
  const float* n1w   = (const float*)d_in[1];
  const float* n1b   = (const float*)d_in[2];
  const float* qkv_w = (const float*)d_in[3];
  const float* qkv_b = (const float*)d_in[4];
  const float* out_w = (const float*)d_in[5];
  const float* out_b = (const float*)d_in[6];
  const float* n2w   = (const float*)d_in[7];
  const float* n2b   = (const float*)d_in[8];
  const float* w1    = (const float*)d_in[9];
  const float* b1    = (const float*)d_in[10];
  const float* w2    = (const float*)d_in[11];
  const float* b2    = (const float*)d_in[12];

  char* ws = (char*)d_ws;
  unsigned short* wbf   = (unsigned short*)(ws);
  unsigned short* wq_bf = wbf;                              // [1536,512]
  unsigned short* wo_bf = (unsigned short*)(ws + 1572864);  // [512,512]
  unsigned short* w1_bf = (unsigned short*)(ws + 2097152);  // [2048,512]
  unsigned short* w2_bf = (unsigned short*)(ws + 4194304);  // [512,2048]
  unsigned short* h_bf  = (unsigned short*)(ws + 6291456);  // [4096,512]
  unsigned short* qkvb  = (unsigned short*)(ws + 10485760); // [4096,1536] bf16
  unsigned short* ao_bf = (unsigned short*)(ws + 23068672); // [4096,512] bf16
  float*          x1    = (float*)(ws + 27262976);          // [4096,512] fp32
  unsigned short* f1_bf = (unsigned short*)(ws + 10485760); // [4096,2048] aliases dead qkv+ao
  float* outp = (float*)d_out;

  cvt_weights<<<3072, 256, 0, stream>>>(qkv_w, out_w, w1, w2, wbf);
  ln_bf16<<<1024, 256, 0, stream>>>(x, n1w, n1b, h_bf);
  gemm_bt<128, 64, 0><<<32 * 24, 256, 0, stream>>>(h_bf, wq_bf, qkv_b, nullptr,
                                                   nullptr, qkvb, 4096, 1536, 512);
  attn_mfma<<<512, 256, 0, stream>>>(qkvb, ao_bf);
  gemm_bt<64, 64, 1><<<64 * 8, 256, 0, stream>>>(ao_bf, wo_bf, out_b, x, x1,
                                                 nullptr, 4096, 512, 512);
  ln_bf16<<<1024, 256, 0, stream>>>(x1, n2w, n2b, h_bf);
  gemm_bt<128, 64, 2><<<32 * 32, 256, 0, stream>>>(h_bf, w1_bf, b1, nullptr,
                                                   nullptr, f1_bf, 4096, 2048, 512);
  gemm_bt<64, 64, 1><<<64 * 8, 256, 0, stream>>>(f1_bf, w2_bf, b2, x1, outp,
                                                 nullptr, 4096, 512, 2048);
}